// Round 10
// baseline (388.481 us; speedup 1.0000x reference)
//
#include <hip/hip_runtime.h>

// All tensors FLOAT32 (proven R5). GEMMs use bf16 MFMA; threshold 0.108 abs,
// measured bf16 GEMM error 0.031. 3-NN selection = lexicographic min-3 of
// (d2, idx) pairs (== lax.top_k stable tie-break), d2 in exact rn form
// ((dx2+dy2)+dz2, no FMA contraction) -- order-independent, so a spatial
// grid may enumerate candidates in any order.

typedef __attribute__((ext_vector_type(8))) short bf16x8;
typedef __attribute__((ext_vector_type(4))) float f32x4;

__device__ __forceinline__ unsigned short f2bf(float f) {
    union { float f; unsigned u; } v; v.f = f;
    return (unsigned short)((v.u + 0x7fffu + ((v.u >> 16) & 1u)) >> 16); // RNE
}
__device__ __forceinline__ unsigned pack2(float a, float b) {
    return (unsigned)f2bf(a) | ((unsigned)f2bf(b) << 16);
}

// ---------- zero helper ----------
__global__ __launch_bounds__(256)
void zero_kernel(int* __restrict__ p, int n) {
    int i = blockIdx.x * 256 + threadIdx.x;
    if (i < n) p[i] = 0;
}

// ---------- grid build: count / scan / scatter ----------
__global__ __launch_bounds__(256)
void bin_count_kernel(const float* __restrict__ pts, int Ns, int G, float invh,
                      int* __restrict__ cnt) {
    int i = blockIdx.x * 256 + threadIdx.x;
    if (i >= 2 * Ns) return;
    int b = (i >= Ns) ? 1 : 0, pp = i - b * Ns; (void)pp;
    float x = pts[i*3], y = pts[i*3+1], z = pts[i*3+2];
    int cx = min(G-1, max(0, (int)(x*invh)));
    int cy = min(G-1, max(0, (int)(y*invh)));
    int cz = min(G-1, max(0, (int)(z*invh)));
    atomicAdd(&cnt[b*G*G*G + (cz*G + cy)*G + cx], 1);
}

__global__ __launch_bounds__(1024)
void scan_kernel(const int* __restrict__ cnt, int* __restrict__ start,
                 int* __restrict__ cur, int ncells) {
    __shared__ int A[2048], B[2048];
    int b = blockIdx.x, t = threadIdx.x;
    const int* c = cnt + b * ncells;
    for (int i = t; i < 2048; i += 1024) A[i] = (i < ncells) ? c[i] : 0;
    __syncthreads();
    int* src = A; int* dst = B;
    for (int off = 1; off < 2048; off <<= 1) {
        for (int i = t; i < 2048; i += 1024)
            dst[i] = src[i] + ((i >= off) ? src[i - off] : 0);
        __syncthreads();
        int* tmp = src; src = dst; dst = tmp;
    }
    int* st = start + b * (ncells + 1);
    int* cu = cur + b * ncells;
    for (int i = t; i < ncells; i += 1024) {
        int ex = (i == 0) ? 0 : src[i - 1];
        st[i] = ex; cu[i] = ex;
    }
    if (t == 0) st[ncells] = src[ncells - 1];
}

__global__ __launch_bounds__(256)
void scatter_kernel(const float* __restrict__ pts, int Ns, int G, float invh,
                    int* __restrict__ cur, float4* __restrict__ sorted) {
    int i = blockIdx.x * 256 + threadIdx.x;
    if (i >= 2 * Ns) return;
    int b = (i >= Ns) ? 1 : 0, p = i - b * Ns;
    float x = pts[i*3], y = pts[i*3+1], z = pts[i*3+2];
    int cx = min(G-1, max(0, (int)(x*invh)));
    int cy = min(G-1, max(0, (int)(y*invh)));
    int cz = min(G-1, max(0, (int)(z*invh)));
    int pos = atomicAdd(&cur[b*G*G*G + (cz*G + cy)*G + cx], 1);
    sorted[b * Ns + pos] = make_float4(x, y, z, __int_as_float(p));
}

// ---------- grid 3-NN query: 1 thread/target, expanding Chebyshev rings ----------
template<int G>
__global__ __launch_bounds__(256)
void nn_query_kernel(const float* __restrict__ tp, int Nt,
                     const float4* __restrict__ sorted, const int* __restrict__ start,
                     int Ns, int* __restrict__ gidx, float* __restrict__ gw) {
    const float h = 70.0f / G, invh = (float)G / 70.0f;
    int t = blockIdx.x * 256 + threadIdx.x;
    int b = blockIdx.y;
    int tg = b * Nt + t;
    float tx = tp[tg*3], ty = tp[tg*3+1], tz = tp[tg*3+2];
    int cx = min(G-1, max(0, (int)(tx*invh)));
    int cy = min(G-1, max(0, (int)(ty*invh)));
    int cz = min(G-1, max(0, (int)(tz*invh)));
    float m0 = 3.4e38f, m1 = 3.4e38f, m2 = 3.4e38f;
    int j0 = 0x7fffffff, j1 = 0x7fffffff, j2 = 0x7fffffff;
    const float4* sb = sorted + b * Ns;
    const int* stb = start + b * (G*G*G + 1);
    for (int R = 0; R < G; ++R) {
        for (int dz = -R; dz <= R; ++dz)
        for (int dy = -R; dy <= R; ++dy)
        for (int dx = -R; dx <= R; ++dx) {
            int ring = max(abs(dx), max(abs(dy), abs(dz)));   // uniform
            if (ring != R) continue;
            int x = cx + dx, y = cy + dy, z = cz + dz;
            bool ok = (unsigned)x < (unsigned)G && (unsigned)y < (unsigned)G &&
                      (unsigned)z < (unsigned)G;
            int c = ok ? (z*G + y)*G + x : 0;
            int p0 = ok ? stb[c] : 0;
            int p1 = ok ? stb[c+1] : 0;
            for (int p = p0; p < p1; ++p) {
                float4 s = sb[p];
                float ddx = tx - s.x, ddy = ty - s.y, ddz = tz - s.z;
                float d2 = __fadd_rn(__fadd_rn(__fmul_rn(ddx,ddx), __fmul_rn(ddy,ddy)),
                                     __fmul_rn(ddz,ddz));
                int idx = __float_as_int(s.w);
                // lexicographic (d2, idx) insertion -- exact top_k semantics
                bool lt0 = (d2 < m0) || (d2 == m0 && idx < j0);
                bool lt1 = (d2 < m1) || (d2 == m1 && idx < j1);
                bool lt2 = (d2 < m2) || (d2 == m2 && idx < j2);
                m2 = lt1 ? m1 : (lt2 ? d2 : m2);  j2 = lt1 ? j1 : (lt2 ? idx : j2);
                m1 = lt0 ? m0 : (lt1 ? d2 : m1);  j1 = lt0 ? j0 : (lt1 ? idx : j1);
                m0 = lt0 ? d2 : m0;               j0 = lt0 ? idx : j0;
            }
        }
        // conservative stop: unseen points are >= dist-to-processed-box-face away
        float fx0 = (cx - R <= 0)     ? 3.4e38f : tx - (float)(cx - R) * h;
        float fx1 = (cx + R >= G - 1) ? 3.4e38f : (float)(cx + R + 1) * h - tx;
        float fy0 = (cy - R <= 0)     ? 3.4e38f : ty - (float)(cy - R) * h;
        float fy1 = (cy + R >= G - 1) ? 3.4e38f : (float)(cy + R + 1) * h - ty;
        float fz0 = (cz - R <= 0)     ? 3.4e38f : tz - (float)(cz - R) * h;
        float fz1 = (cz + R >= G - 1) ? 3.4e38f : (float)(cz + R + 1) * h - tz;
        float dl = fminf(fminf(fminf(fx0, fx1), fminf(fy0, fy1)), fminf(fz0, fz1));
        if (m2 < 3.3e38f && (dl > 1.0e19f || m2 <= dl * dl * 0.9999f)) break;
    }
    float d0 = sqrtf(fmaxf(m0, 0.f));
    float d1 = sqrtf(fmaxf(m1, 0.f));
    float d2s = sqrtf(fmaxf(m2, 0.f));
    float w0 = 1.f / (d0 + 1e-8f);
    float w1 = 1.f / (d1 + 1e-8f);
    float w2 = 1.f / (d2s + 1e-8f);
    float wsum = w0 + w1 + w2;
    gidx[tg*3] = j0; gidx[tg*3+1] = j1; gidx[tg*3+2] = j2;
    gw[tg*3] = w0 / wsum; gw[tg*3+1] = w1 / wsum; gw[tg*3+2] = w2 / wsum;
}

// ---------- gather: weighted feature sum (vectorized, R9-proven pattern) ----------
__global__ __launch_bounds__(256)
void nn_gather_kernel(const float* __restrict__ feats, const int* __restrict__ gidx,
                      const float* __restrict__ gw, float* __restrict__ out,
                      int Nt, int Ns) {
    int tid = threadIdx.x;
    int tt = blockIdx.x * 16 + (tid >> 4);
    int b = blockIdx.y;
    int cp = (tid & 15) * 8;
    int tg = b * Nt + tt;
    int j0 = gidx[tg*3], j1 = gidx[tg*3+1], j2 = gidx[tg*3+2];
    float w0 = gw[tg*3], w1 = gw[tg*3+1], w2 = gw[tg*3+2];
    int base = b * Ns * 128;
    const float4* F0 = (const float4*)&feats[base + j0*128 + cp];
    const float4* F1 = (const float4*)&feats[base + j1*128 + cp];
    const float4* F2 = (const float4*)&feats[base + j2*128 + cp];
    float4* O = (float4*)&out[tg*128 + cp];
    #pragma unroll
    for (int q = 0; q < 2; ++q) {
        float4 a = F0[q], bb = F1[q], cc = F2[q];
        float4 o;
        o.x = w0*a.x + w1*bb.x + w2*cc.x;
        o.y = w0*a.y + w1*bb.y + w2*cc.y;
        o.z = w0*a.z + w1*bb.z + w2*cc.z;
        o.w = w0*a.w + w1*bb.w + w2*cc.w;
        O[q] = o;
    }
}

// ---------- GEMM A (MFMA bf16, +fused BN stats): H = [L|R] @ W^T ---------- (R9-proven)
__global__ __launch_bounds__(256)
void gemm_a_kernel(const float* __restrict__ L, const float* __restrict__ R,
                   const float* __restrict__ W, float* __restrict__ H,
                   float* __restrict__ st) {
    __shared__ short Asm[4096];   // 128 rows x 32 k
    __shared__ short Bsm[2048];   // 64 cols x 32 k
    int tid = threadIdx.x;
    int lane = tid & 63, w = tid >> 6;
    int m16 = lane & 15, quad = lane >> 4;
    int rowBase = blockIdx.y * 128;
    int colBase = blockIdx.x * 64;
    f32x4 acc[2][4] = {};
    for (int k0 = 0; k0 < 256; k0 += 32) {
        #pragma unroll
        for (int i = 0; i < 2; ++i) {
            int u = tid + i * 256;
            int r = u >> 2, g = u & 3;
            const float* p = (k0 < 128) ? &L[(rowBase + r) * 128 + k0 + g * 8]
                                        : &R[(rowBase + r) * 128 + (k0 - 128) + g * 8];
            float4 x = *(const float4*)p, y = *(const float4*)(p + 4);
            uint4 pk = make_uint4(pack2(x.x, x.y), pack2(x.z, x.w),
                                  pack2(y.x, y.y), pack2(y.z, y.w));
            int blk = (r >> 4) * 64 + (r & 15) * 4 + g;
            *(uint4*)&Asm[blk * 8] = pk;
        }
        {
            int n = tid >> 2, g = tid & 3;
            const float* p = &W[(colBase + n) * 256 + k0 + g * 8];
            float4 x = *(const float4*)p, y = *(const float4*)(p + 4);
            uint4 pk = make_uint4(pack2(x.x, x.y), pack2(x.z, x.w),
                                  pack2(y.x, y.y), pack2(y.z, y.w));
            int blk = (n >> 4) * 64 + (n & 15) * 4 + g;
            *(uint4*)&Bsm[blk * 8] = pk;
        }
        __syncthreads();
        bf16x8 a0 = *(const bf16x8*)&Asm[((2 * w + 0) * 64 + m16 * 4 + quad) * 8];
        bf16x8 a1 = *(const bf16x8*)&Asm[((2 * w + 1) * 64 + m16 * 4 + quad) * 8];
        #pragma unroll
        for (int ct = 0; ct < 4; ++ct) {
            bf16x8 bf = *(const bf16x8*)&Bsm[(ct * 64 + m16 * 4 + quad) * 8];
            acc[0][ct] = __builtin_amdgcn_mfma_f32_16x16x32_bf16(a0, bf, acc[0][ct], 0, 0, 0);
            acc[1][ct] = __builtin_amdgcn_mfma_f32_16x16x32_bf16(a1, bf, acc[1][ct], 0, 0, 0);
        }
        __syncthreads();
    }
    #pragma unroll
    for (int rt = 0; rt < 2; ++rt)
        #pragma unroll
        for (int r = 0; r < 4; ++r) {
            int row = rowBase + (2 * w + rt) * 16 + quad * 4 + r;
            #pragma unroll
            for (int ct = 0; ct < 4; ++ct)
                H[row * 128 + colBase + ct * 16 + m16] = acc[rt][ct][r];
        }
    float* ssum = (float*)Asm;
    float* ssq  = (float*)Asm + 1024;
    #pragma unroll
    for (int ct = 0; ct < 4; ++ct) {
        float s = 0.f, q = 0.f;
        #pragma unroll
        for (int rt = 0; rt < 2; ++rt)
            #pragma unroll
            for (int r = 0; r < 4; ++r) {
                float v = acc[rt][ct][r];
                s += v; q += v * v;
            }
        ssum[(w * 4 + quad) * 64 + ct * 16 + m16] = s;
        ssq [(w * 4 + quad) * 64 + ct * 16 + m16] = q;
    }
    __syncthreads();
    if (tid < 64) {
        float s = 0.f, q = 0.f;
        #pragma unroll
        for (int i = 0; i < 16; ++i) { s += ssum[i * 64 + tid]; q += ssq[i * 64 + tid]; }
        atomicAdd(&st[colBase + tid], s);
        atomicAdd(&st[128 + colBase + tid], q);
    }
}

__global__ __launch_bounds__(128)
void finalize_kernel(const float* __restrict__ st, const float* __restrict__ g,
                     const float* __restrict__ b, float invN, float* __restrict__ ss) {
    int c = threadIdx.x;
    float mu = st[c] * invN;
    float var = st[128 + c] * invN - mu * mu;
    float rstd = rsqrtf(fmaxf(var, 0.f) + 1e-5f);
    float sc = rstd * g[c];
    ss[c] = sc;
    ss[128 + c] = b[c] - mu * sc;
}

// ---------- GEMM B (MFMA bf16): out = relu(BN(H)) @ W^T + bias ---------- (R9-proven)
__global__ __launch_bounds__(256)
void gemm_b_kernel(const float* __restrict__ Hin, const float* __restrict__ ss,
                   const float* __restrict__ W, const float* __restrict__ bias,
                   float* __restrict__ out) {
    __shared__ short Asm[4096];
    __shared__ short Bsm[2048];
    __shared__ float ssc[128], ssf[128];
    int tid = threadIdx.x;
    if (tid < 128) { ssc[tid] = ss[tid]; ssf[tid] = ss[128 + tid]; }
    __syncthreads();
    int lane = tid & 63, w = tid >> 6;
    int m16 = lane & 15, quad = lane >> 4;
    int rowBase = blockIdx.y * 128;
    int colBase = blockIdx.x * 64;
    f32x4 acc[2][4] = {};
    for (int k0 = 0; k0 < 128; k0 += 32) {
        #pragma unroll
        for (int i = 0; i < 2; ++i) {
            int u = tid + i * 256;
            int r = u >> 2, g = u & 3;
            int c = k0 + g * 8;
            const float* p = &Hin[(rowBase + r) * 128 + c];
            float4 x = *(const float4*)p, y = *(const float4*)(p + 4);
            float h0 = fmaxf(x.x * ssc[c+0] + ssf[c+0], 0.f);
            float h1 = fmaxf(x.y * ssc[c+1] + ssf[c+1], 0.f);
            float h2 = fmaxf(x.z * ssc[c+2] + ssf[c+2], 0.f);
            float h3 = fmaxf(x.w * ssc[c+3] + ssf[c+3], 0.f);
            float h4 = fmaxf(y.x * ssc[c+4] + ssf[c+4], 0.f);
            float h5 = fmaxf(y.y * ssc[c+5] + ssf[c+5], 0.f);
            float h6 = fmaxf(y.z * ssc[c+6] + ssf[c+6], 0.f);
            float h7 = fmaxf(y.w * ssc[c+7] + ssf[c+7], 0.f);
            uint4 pk = make_uint4(pack2(h0, h1), pack2(h2, h3),
                                  pack2(h4, h5), pack2(h6, h7));
            int blk = (r >> 4) * 64 + (r & 15) * 4 + g;
            *(uint4*)&Asm[blk * 8] = pk;
        }
        {
            int n = tid >> 2, g = tid & 3;
            const float* p = &W[(colBase + n) * 128 + k0 + g * 8];
            float4 x = *(const float4*)p, y = *(const float4*)(p + 4);
            uint4 pk = make_uint4(pack2(x.x, x.y), pack2(x.z, x.w),
                                  pack2(y.x, y.y), pack2(y.z, y.w));
            int blk = (n >> 4) * 64 + (n & 15) * 4 + g;
            *(uint4*)&Bsm[blk * 8] = pk;
        }
        __syncthreads();
        bf16x8 a0 = *(const bf16x8*)&Asm[((2 * w + 0) * 64 + m16 * 4 + quad) * 8];
        bf16x8 a1 = *(const bf16x8*)&Asm[((2 * w + 1) * 64 + m16 * 4 + quad) * 8];
        #pragma unroll
        for (int ct = 0; ct < 4; ++ct) {
            bf16x8 bf = *(const bf16x8*)&Bsm[(ct * 64 + m16 * 4 + quad) * 8];
            acc[0][ct] = __builtin_amdgcn_mfma_f32_16x16x32_bf16(a0, bf, acc[0][ct], 0, 0, 0);
            acc[1][ct] = __builtin_amdgcn_mfma_f32_16x16x32_bf16(a1, bf, acc[1][ct], 0, 0, 0);
        }
        __syncthreads();
    }
    #pragma unroll
    for (int ct = 0; ct < 4; ++ct) {
        float bv = bias[colBase + ct * 16 + m16];
        #pragma unroll
        for (int rt = 0; rt < 2; ++rt)
            #pragma unroll
            for (int r = 0; r < 4; ++r) {
                int row = rowBase + (2 * w + rt) * 16 + quad * 4 + r;
                out[row * 128 + colBase + ct * 16 + m16] = acc[rt][ct][r] + bv;
            }
    }
}

extern "C" void kernel_launch(void* const* d_in, const int* in_sizes, int n_in,
                              void* d_out, int out_size, void* d_ws, size_t ws_size,
                              hipStream_t stream) {
    const float* pts_r1 = (const float*)d_in[0];   // (2,8192,3)
    const float* pts_r2 = (const float*)d_in[1];   // (2,4096,3)
    const float* pts_r4 = (const float*)d_in[2];   // (2,2048,3)
    const float* feat0  = (const float*)d_in[3];   // (16384,128)
    const float* feat1  = (const float*)d_in[4];   // (8192,128)
    const float* feat2  = (const float*)d_in[5];   // (4096,128)
    const float* w3a = (const float*)d_in[6];      // (128,256)
    const float* g3  = (const float*)d_in[7];
    const float* b3  = (const float*)d_in[8];
    const float* w3b = (const float*)d_in[9];      // (128,128)
    const float* bb3 = (const float*)d_in[10];
    const float* w4a = (const float*)d_in[11];     // (128,256)
    const float* g4  = (const float*)d_in[12];
    const float* b4  = (const float*)d_in[13];
    const float* w4b = (const float*)d_in[14];     // (128,128)
    const float* bb4 = (const float*)d_in[15];

    // ws layout (floats), 17.33 MB total -- under proven-safe 21.4 MB.
    float* wsf = (float*)d_ws;
    float4* sorted = (float4*)(wsf + 0);      // 32768 floats (max 2x4096 float4)
    int*   gidx  = (int*)(wsf + 32768);       // 49152 (max 16384x3)
    float* gw    = wsf + 81920;               // 49152
    int*   cnt   = (int*)(wsf + 131072);      // 2048 (max 2x1000)
    int*   start = (int*)(wsf + 133120);      // 2048 (max 2x1001)
    int*   cur   = (int*)(wsf + 135168);      // 2048
    float* st1   = wsf + 137216;              // 256 (sum | sumsq)
    float* ss1   = wsf + 137472;              // 256 (scale | shift)
    float* st2   = wsf + 137728;              // 256
    float* ss2   = wsf + 137984;              // 256  -> 138240
    float* f2i   = wsf + 138240;              // 8192*128
    float* H1    = wsf + 1186816;             // 8192*128
    float* n3    = wsf + 2235392;             // 8192*128
    float* n3i   = wsf + 138240;              // 16384*128 (over f2i+H1, both dead)
    float* H2    = wsf + 2235392;             // 16384*128 (over n3, dead by then)

    const int G4 = 8,  N4 = 2048;   // grid for pts_r4 sources (interp #1)
    const int G2 = 10, N2 = 4096;   // grid for pts_r2 sources (interp #2)
    const float invh4 = (float)G4 / 70.0f, invh2 = (float)G2 / 70.0f;

    // stats zero + grid4 build
    zero_kernel<<<4, 256, 0, stream>>>((int*)st1, 1024);
    zero_kernel<<<8, 256, 0, stream>>>(cnt, 2 * G4*G4*G4);
    bin_count_kernel<<<16, 256, 0, stream>>>(pts_r4, N4, G4, invh4, cnt);
    scan_kernel<<<2, 1024, 0, stream>>>(cnt, start, cur, G4*G4*G4);
    scatter_kernel<<<16, 256, 0, stream>>>(pts_r4, N4, G4, invh4, cur, sorted);
    // interp #1: feat2 (pts_r4 grid) -> pts_r2 targets (Nt=4096/batch)
    nn_query_kernel<G4><<<dim3(16, 2), 256, 0, stream>>>(pts_r2, 4096, sorted, start,
                                                         N4, gidx, gw);
    nn_gather_kernel<<<dim3(256, 2), 256, 0, stream>>>(feat2, gidx, gw, f2i, 4096, N4);
    // fnode 3
    gemm_a_kernel<<<dim3(2, 64), 256, 0, stream>>>(feat1, f2i, w3a, H1, st1);
    finalize_kernel<<<1, 128, 0, stream>>>(st1, g3, b3, 1.f / 8192.f, ss1);
    gemm_b_kernel<<<dim3(2, 64), 256, 0, stream>>>(H1, ss1, w3b, bb3, n3);
    // grid2 build
    zero_kernel<<<8, 256, 0, stream>>>(cnt, 2 * G2*G2*G2);
    bin_count_kernel<<<32, 256, 0, stream>>>(pts_r2, N2, G2, invh2, cnt);
    scan_kernel<<<2, 1024, 0, stream>>>(cnt, start, cur, G2*G2*G2);
    scatter_kernel<<<32, 256, 0, stream>>>(pts_r2, N2, G2, invh2, cur, sorted);
    // interp #2: n3 (pts_r2 grid) -> pts_r1 targets (Nt=8192/batch)
    nn_query_kernel<G2><<<dim3(32, 2), 256, 0, stream>>>(pts_r1, 8192, sorted, start,
                                                         N2, gidx, gw);
    nn_gather_kernel<<<dim3(512, 2), 256, 0, stream>>>(n3, gidx, gw, n3i, 8192, N2);
    // fnode 4
    gemm_a_kernel<<<dim3(2, 128), 256, 0, stream>>>(feat0, n3i, w4a, H2, st2);
    finalize_kernel<<<1, 128, 0, stream>>>(st2, g4, b4, 1.f / 16384.f, ss2);
    gemm_b_kernel<<<dim3(2, 128), 256, 0, stream>>>(H2, ss2, w4b, bb4, (float*)d_out);
}

// Round 11
// 217.819 us; speedup vs baseline: 1.7835x; 1.7835x over previous
//
#include <hip/hip_runtime.h>

// All tensors FLOAT32 (proven R5). GEMMs: bf16 MFMA (err 0.031 < 0.108 thr).
// 3-NN = lexicographic min-3 of (d2, idx) == lax.top_k stable tie-break;
// d2 exact rn form ((dx2+dy2)+dz2). Set semantics -> any enumeration order.
// Grid cells along x are contiguous in `sorted` (scatter fills cells in index
// order), so each ring = ~10 contiguous ranges, dealt round-robin to 8 lanes
// per target; per-lane top-3 lists are disjoint -> shfl butterfly lex-merge.

typedef __attribute__((ext_vector_type(8))) short bf16x8;
typedef __attribute__((ext_vector_type(4))) float f32x4;

__device__ __forceinline__ unsigned short f2bf(float f) {
    union { float f; unsigned u; } v; v.f = f;
    return (unsigned short)((v.u + 0x7fffu + ((v.u >> 16) & 1u)) >> 16); // RNE
}
__device__ __forceinline__ unsigned pack2(float a, float b) {
    return (unsigned)f2bf(a) | ((unsigned)f2bf(b) << 16);
}

// ---------- fused grid build: 4 blocks = {grid4 b0, grid4 b1, grid2 b0, grid2 b1} ----------
// Per block: LDS count -> LDS Hillis-Steele scan -> LDS-atomic scatter.
// Also zeroes BN stat accumulators (blocks 0/1).
__global__ __launch_bounds__(1024)
void build_grid_kernel(const float* __restrict__ p4, const float* __restrict__ p2,
                       float4* __restrict__ sorted4, int* __restrict__ start4,
                       float4* __restrict__ sorted2, int* __restrict__ start2,
                       float* __restrict__ st1, float* __restrict__ st2) {
    __shared__ int A[1024], B[1024];
    int bx = blockIdx.x, t = threadIdx.x;
    int isG2 = bx >> 1, b = bx & 1;
    const float* pts = (isG2 ? p2 : p4);
    int Ns = isG2 ? 4096 : 2048;
    int G  = isG2 ? 10 : 8;
    int nc = G * G * G;
    float invh = (float)G / 70.0f;
    float4* sorted = (isG2 ? sorted2 : sorted4) + b * Ns;
    int* start = (isG2 ? start2 : start4) + b * (nc + 1);
    const float* pb = pts + b * Ns * 3;

    if (bx == 0 && t < 256) st1[t] = 0.f;
    if (bx == 1 && t < 256) st2[t] = 0.f;

    A[t] = 0;
    __syncthreads();
    for (int i = t; i < Ns; i += 1024) {
        float x = pb[i*3], y = pb[i*3+1], z = pb[i*3+2];
        int cx = min(G-1, max(0, (int)(x*invh)));
        int cy = min(G-1, max(0, (int)(y*invh)));
        int cz = min(G-1, max(0, (int)(z*invh)));
        atomicAdd(&A[(cz*G + cy)*G + cx], 1);
    }
    __syncthreads();
    int* src = A; int* dst = B;
    for (int off = 1; off < 1024; off <<= 1) {
        dst[t] = src[t] + ((t >= off) ? src[t - off] : 0);
        __syncthreads();
        int* tmp = src; src = dst; dst = tmp;
    }
    // src = inclusive scan; dst = scratch for 'cur'
    int ex = (t == 0) ? 0 : src[t - 1];
    if (t < nc) { start[t] = ex; dst[t] = ex; }
    if (t == 0) start[nc] = src[nc - 1];
    __syncthreads();
    for (int i = t; i < Ns; i += 1024) {
        float x = pb[i*3], y = pb[i*3+1], z = pb[i*3+2];
        int cx = min(G-1, max(0, (int)(x*invh)));
        int cy = min(G-1, max(0, (int)(y*invh)));
        int cz = min(G-1, max(0, (int)(z*invh)));
        int pos = atomicAdd(&dst[(cz*G + cy)*G + cx], 1);
        sorted[pos] = make_float4(x, y, z, __int_as_float(i));
    }
}

// ---------- fused 3-NN query+gather: 8 lanes/target, 32 targets/block ----------
template<int G>
__global__ __launch_bounds__(256)
void nn_query_gather_kernel(const float* __restrict__ tp, int Nt,
                            const float4* __restrict__ sorted,
                            const int* __restrict__ start, int Ns,
                            const float* __restrict__ feats, float* __restrict__ out) {
    const float h = 70.0f / G, invh = (float)G / 70.0f;
    const int CAP = 6;
    int tid = threadIdx.x;
    int l = tid & 7, g = tid >> 3;
    int b = blockIdx.y;
    int t = blockIdx.x * 32 + g;
    int tg = b * Nt + t;
    float tx = tp[tg*3], ty = tp[tg*3+1], tz = tp[tg*3+2];
    int cx = min(G-1, max(0, (int)(tx*invh)));
    int cy = min(G-1, max(0, (int)(ty*invh)));
    int cz = min(G-1, max(0, (int)(tz*invh)));
    const float4* sb = sorted + b * Ns;
    const int* stb = start + b * (G*G*G + 1);

    float m0 = 3.4e38f, m1 = 3.4e38f, m2 = 3.4e38f;
    int j0 = 0x7fffffff, j1 = 0x7fffffff, j2 = 0x7fffffff;

    auto lexins = [&](float d, int ix) {
        bool lt0 = (d < m0) || (d == m0 && ix < j0);
        bool lt1 = (d < m1) || (d == m1 && ix < j1);
        bool lt2 = (d < m2) || (d == m2 && ix < j2);
        m2 = lt1 ? m1 : (lt2 ? d : m2);  j2 = lt1 ? j1 : (lt2 ? ix : j2);
        m1 = lt0 ? m0 : (lt1 ? d : m1);  j1 = lt0 ? j0 : (lt1 ? ix : j1);
        m0 = lt0 ? d : m0;               j0 = lt0 ? ix : j0;
    };
    auto scanRange = [&](int p0, int p1) {
        for (int p = p0; p < p1; ++p) {
            float4 s = sb[p];
            float ddx = tx - s.x, ddy = ty - s.y, ddz = tz - s.z;
            float d2 = __fadd_rn(__fadd_rn(__fmul_rn(ddx,ddx), __fmul_rn(ddy,ddy)),
                                 __fmul_rn(ddz,ddz));
            lexins(d2, __float_as_int(s.w));
        }
    };

    for (int R = 0; R < G; ++R) {
        int myp0[CAP], myp1[CAP];
        int nm = 0, k = 0;
        if (R == 0) {
            int c = (cz*G + cy)*G + cx;
            if ((k & 7) == l) { myp0[0] = stb[c]; myp1[0] = stb[c+1]; nm = 1; }
            ++k;
        } else {
            for (int dz = -R; dz <= R; ++dz) {
                int z = cz + dz;
                if (z < 0 || z >= G) continue;
                for (int dy = -R; dy <= R; ++dy) {
                    int y = cy + dy;
                    if (y < 0 || y >= G) continue;
                    int rowb = (z*G + y)*G;
                    bool edge = (dz == -R) || (dz == R) || (dy == -R) || (dy == R);
                    if (edge) {
                        int x0 = max(cx - R, 0), x1 = min(cx + R, G - 1);
                        if ((k & 7) == l) {
                            int p0 = stb[rowb + x0], p1 = stb[rowb + x1 + 1];
                            if (nm < CAP) { myp0[nm] = p0; myp1[nm] = p1; ++nm; }
                            else scanRange(p0, p1);          // overflow: rare, inline
                        }
                        ++k;
                    } else {
                        int xm = cx - R, xp = cx + R;
                        if (xm >= 0) {
                            if ((k & 7) == l) {
                                int p0 = stb[rowb + xm], p1 = stb[rowb + xm + 1];
                                if (nm < CAP) { myp0[nm] = p0; myp1[nm] = p1; ++nm; }
                                else scanRange(p0, p1);
                            }
                            ++k;
                        }
                        if (xp < G) {
                            if ((k & 7) == l) {
                                int p0 = stb[rowb + xp], p1 = stb[rowb + xp + 1];
                                if (nm < CAP) { myp0[nm] = p0; myp1[nm] = p1; ++nm; }
                                else scanRange(p0, p1);
                            }
                            ++k;
                        }
                    }
                }
            }
        }
        // phase B: all lanes stream their latched ranges concurrently
        for (int q = 0; q < nm; ++q) scanRange(myp0[q], myp1[q]);

        // group-wide 3rd-min (value-only butterfly; per-lane lists are disjoint)
        float t0 = m0, t1 = m1, t2 = m2;
        #pragma unroll
        for (int mask = 1; mask <= 4; mask <<= 1) {
            float o0 = __shfl_xor(t0, mask);
            float o1 = __shfl_xor(t1, mask);
            float o2 = __shfl_xor(t2, mask);
            bool lt;
            lt = o0 < t0; { float n0 = lt ? o0 : t0, n1 = lt ? t0 : t1, n2 = lt ? t1 : t2;
                            bool l1 = o0 < t1 && !lt; n1 = l1 ? o0 : n1; n2 = l1 ? t1 : n2;
                            bool l2 = o0 < t2 && !l1 && !lt; n2 = l2 ? o0 : n2;
                            t0 = n0; t1 = n1; t2 = n2; }
            lt = o1 < t0; { float n0 = lt ? o1 : t0, n1 = lt ? t0 : t1, n2 = lt ? t1 : t2;
                            bool l1 = o1 < t1 && !lt; n1 = l1 ? o1 : n1; n2 = l1 ? t1 : n2;
                            bool l2 = o1 < t2 && !l1 && !lt; n2 = l2 ? o1 : n2;
                            t0 = n0; t1 = n1; t2 = n2; }
            lt = o2 < t0; { float n0 = lt ? o2 : t0, n1 = lt ? t0 : t1, n2 = lt ? t1 : t2;
                            bool l1 = o2 < t1 && !lt; n1 = l1 ? o2 : n1; n2 = l1 ? t1 : n2;
                            bool l2 = o2 < t2 && !l1 && !lt; n2 = l2 ? o2 : n2;
                            t0 = n0; t1 = n1; t2 = n2; }
        }
        // conservative stop (R10-proven): unseen >= dist to processed-box face
        float fx0 = (cx - R <= 0)     ? 3.4e38f : tx - (float)(cx - R) * h;
        float fx1 = (cx + R >= G - 1) ? 3.4e38f : (float)(cx + R + 1) * h - tx;
        float fy0 = (cy - R <= 0)     ? 3.4e38f : ty - (float)(cy - R) * h;
        float fy1 = (cy + R >= G - 1) ? 3.4e38f : (float)(cy + R + 1) * h - ty;
        float fz0 = (cz - R <= 0)     ? 3.4e38f : tz - (float)(cz - R) * h;
        float fz1 = (cz + R >= G - 1) ? 3.4e38f : (float)(cz + R + 1) * h - tz;
        float dl = fminf(fminf(fminf(fx0, fx1), fminf(fy0, fy1)), fminf(fz0, fz1));
        if (t2 < 3.3e38f && (dl > 1.0e19f || t2 <= dl * dl * 0.9999f)) break;
    }

    // final exact lex merge across the 8 lanes (disjoint multisets)
    #pragma unroll
    for (int mask = 1; mask <= 4; mask <<= 1) {
        float o0 = __shfl_xor(m0, mask), o1 = __shfl_xor(m1, mask), o2 = __shfl_xor(m2, mask);
        int   q0 = __shfl_xor(j0, mask), q1 = __shfl_xor(j1, mask), q2 = __shfl_xor(j2, mask);
        lexins(o0, q0); lexins(o1, q1); lexins(o2, q2);
    }

    float d0 = sqrtf(fmaxf(m0, 0.f));
    float d1 = sqrtf(fmaxf(m1, 0.f));
    float d2s = sqrtf(fmaxf(m2, 0.f));
    float w0 = 1.f / (d0 + 1e-8f);
    float w1 = 1.f / (d1 + 1e-8f);
    float w2 = 1.f / (d2s + 1e-8f);
    float wsum = w0 + w1 + w2;
    w0 /= wsum; w1 /= wsum; w2 /= wsum;

    // fused gather: lane l covers channels [l*16, l*16+16)
    int base = b * Ns * 128;
    const float4* F0 = (const float4*)&feats[base + j0 * 128];
    const float4* F1 = (const float4*)&feats[base + j1 * 128];
    const float4* F2 = (const float4*)&feats[base + j2 * 128];
    float4* O = (float4*)&out[tg * 128];
    #pragma unroll
    for (int q = 0; q < 4; ++q) {
        int ci = l * 4 + q;
        float4 a = F0[ci], bb = F1[ci], cc = F2[ci];
        float4 o;
        o.x = w0*a.x + w1*bb.x + w2*cc.x;
        o.y = w0*a.y + w1*bb.y + w2*cc.y;
        o.z = w0*a.z + w1*bb.z + w2*cc.z;
        o.w = w0*a.w + w1*bb.w + w2*cc.w;
        O[ci] = o;
    }
}

// ---------- GEMM A (MFMA bf16, +fused BN stats): H = [L|R] @ W^T ---------- (R9-proven)
__global__ __launch_bounds__(256)
void gemm_a_kernel(const float* __restrict__ L, const float* __restrict__ R,
                   const float* __restrict__ W, float* __restrict__ H,
                   float* __restrict__ st) {
    __shared__ short Asm[4096];
    __shared__ short Bsm[2048];
    int tid = threadIdx.x;
    int lane = tid & 63, w = tid >> 6;
    int m16 = lane & 15, quad = lane >> 4;
    int rowBase = blockIdx.y * 128;
    int colBase = blockIdx.x * 64;
    f32x4 acc[2][4] = {};
    for (int k0 = 0; k0 < 256; k0 += 32) {
        #pragma unroll
        for (int i = 0; i < 2; ++i) {
            int u = tid + i * 256;
            int r = u >> 2, g = u & 3;
            const float* p = (k0 < 128) ? &L[(rowBase + r) * 128 + k0 + g * 8]
                                        : &R[(rowBase + r) * 128 + (k0 - 128) + g * 8];
            float4 x = *(const float4*)p, y = *(const float4*)(p + 4);
            uint4 pk = make_uint4(pack2(x.x, x.y), pack2(x.z, x.w),
                                  pack2(y.x, y.y), pack2(y.z, y.w));
            int blk = (r >> 4) * 64 + (r & 15) * 4 + g;
            *(uint4*)&Asm[blk * 8] = pk;
        }
        {
            int n = tid >> 2, g = tid & 3;
            const float* p = &W[(colBase + n) * 256 + k0 + g * 8];
            float4 x = *(const float4*)p, y = *(const float4*)(p + 4);
            uint4 pk = make_uint4(pack2(x.x, x.y), pack2(x.z, x.w),
                                  pack2(y.x, y.y), pack2(y.z, y.w));
            int blk = (n >> 4) * 64 + (n & 15) * 4 + g;
            *(uint4*)&Bsm[blk * 8] = pk;
        }
        __syncthreads();
        bf16x8 a0 = *(const bf16x8*)&Asm[((2 * w + 0) * 64 + m16 * 4 + quad) * 8];
        bf16x8 a1 = *(const bf16x8*)&Asm[((2 * w + 1) * 64 + m16 * 4 + quad) * 8];
        #pragma unroll
        for (int ct = 0; ct < 4; ++ct) {
            bf16x8 bf = *(const bf16x8*)&Bsm[(ct * 64 + m16 * 4 + quad) * 8];
            acc[0][ct] = __builtin_amdgcn_mfma_f32_16x16x32_bf16(a0, bf, acc[0][ct], 0, 0, 0);
            acc[1][ct] = __builtin_amdgcn_mfma_f32_16x16x32_bf16(a1, bf, acc[1][ct], 0, 0, 0);
        }
        __syncthreads();
    }
    #pragma unroll
    for (int rt = 0; rt < 2; ++rt)
        #pragma unroll
        for (int r = 0; r < 4; ++r) {
            int row = rowBase + (2 * w + rt) * 16 + quad * 4 + r;
            #pragma unroll
            for (int ct = 0; ct < 4; ++ct)
                H[row * 128 + colBase + ct * 16 + m16] = acc[rt][ct][r];
        }
    float* ssum = (float*)Asm;
    float* ssq  = (float*)Asm + 1024;
    #pragma unroll
    for (int ct = 0; ct < 4; ++ct) {
        float s = 0.f, q = 0.f;
        #pragma unroll
        for (int rt = 0; rt < 2; ++rt)
            #pragma unroll
            for (int r = 0; r < 4; ++r) {
                float v = acc[rt][ct][r];
                s += v; q += v * v;
            }
        ssum[(w * 4 + quad) * 64 + ct * 16 + m16] = s;
        ssq [(w * 4 + quad) * 64 + ct * 16 + m16] = q;
    }
    __syncthreads();
    if (tid < 64) {
        float s = 0.f, q = 0.f;
        #pragma unroll
        for (int i = 0; i < 16; ++i) { s += ssum[i * 64 + tid]; q += ssq[i * 64 + tid]; }
        atomicAdd(&st[colBase + tid], s);
        atomicAdd(&st[128 + colBase + tid], q);
    }
}

__global__ __launch_bounds__(128)
void finalize_kernel(const float* __restrict__ st, const float* __restrict__ g,
                     const float* __restrict__ b, float invN, float* __restrict__ ss) {
    int c = threadIdx.x;
    float mu = st[c] * invN;
    float var = st[128 + c] * invN - mu * mu;
    float rstd = rsqrtf(fmaxf(var, 0.f) + 1e-5f);
    float sc = rstd * g[c];
    ss[c] = sc;
    ss[128 + c] = b[c] - mu * sc;
}

// ---------- GEMM B (MFMA bf16): out = relu(BN(H)) @ W^T + bias ---------- (R9-proven)
__global__ __launch_bounds__(256)
void gemm_b_kernel(const float* __restrict__ Hin, const float* __restrict__ ss,
                   const float* __restrict__ W, const float* __restrict__ bias,
                   float* __restrict__ out) {
    __shared__ short Asm[4096];
    __shared__ short Bsm[2048];
    __shared__ float ssc[128], ssf[128];
    int tid = threadIdx.x;
    if (tid < 128) { ssc[tid] = ss[tid]; ssf[tid] = ss[128 + tid]; }
    __syncthreads();
    int lane = tid & 63, w = tid >> 6;
    int m16 = lane & 15, quad = lane >> 4;
    int rowBase = blockIdx.y * 128;
    int colBase = blockIdx.x * 64;
    f32x4 acc[2][4] = {};
    for (int k0 = 0; k0 < 128; k0 += 32) {
        #pragma unroll
        for (int i = 0; i < 2; ++i) {
            int u = tid + i * 256;
            int r = u >> 2, g = u & 3;
            int c = k0 + g * 8;
            const float* p = &Hin[(rowBase + r) * 128 + c];
            float4 x = *(const float4*)p, y = *(const float4*)(p + 4);
            float h0 = fmaxf(x.x * ssc[c+0] + ssf[c+0], 0.f);
            float h1 = fmaxf(x.y * ssc[c+1] + ssf[c+1], 0.f);
            float h2 = fmaxf(x.z * ssc[c+2] + ssf[c+2], 0.f);
            float h3 = fmaxf(x.w * ssc[c+3] + ssf[c+3], 0.f);
            float h4 = fmaxf(y.x * ssc[c+4] + ssf[c+4], 0.f);
            float h5 = fmaxf(y.y * ssc[c+5] + ssf[c+5], 0.f);
            float h6 = fmaxf(y.z * ssc[c+6] + ssf[c+6], 0.f);
            float h7 = fmaxf(y.w * ssc[c+7] + ssf[c+7], 0.f);
            uint4 pk = make_uint4(pack2(h0, h1), pack2(h2, h3),
                                  pack2(h4, h5), pack2(h6, h7));
            int blk = (r >> 4) * 64 + (r & 15) * 4 + g;
            *(uint4*)&Asm[blk * 8] = pk;
        }
        {
            int n = tid >> 2, g = tid & 3;
            const float* p = &W[(colBase + n) * 128 + k0 + g * 8];
            float4 x = *(const float4*)p, y = *(const float4*)(p + 4);
            uint4 pk = make_uint4(pack2(x.x, x.y), pack2(x.z, x.w),
                                  pack2(y.x, y.y), pack2(y.z, y.w));
            int blk = (n >> 4) * 64 + (n & 15) * 4 + g;
            *(uint4*)&Bsm[blk * 8] = pk;
        }
        __syncthreads();
        bf16x8 a0 = *(const bf16x8*)&Asm[((2 * w + 0) * 64 + m16 * 4 + quad) * 8];
        bf16x8 a1 = *(const bf16x8*)&Asm[((2 * w + 1) * 64 + m16 * 4 + quad) * 8];
        #pragma unroll
        for (int ct = 0; ct < 4; ++ct) {
            bf16x8 bf = *(const bf16x8*)&Bsm[(ct * 64 + m16 * 4 + quad) * 8];
            acc[0][ct] = __builtin_amdgcn_mfma_f32_16x16x32_bf16(a0, bf, acc[0][ct], 0, 0, 0);
            acc[1][ct] = __builtin_amdgcn_mfma_f32_16x16x32_bf16(a1, bf, acc[1][ct], 0, 0, 0);
        }
        __syncthreads();
    }
    #pragma unroll
    for (int ct = 0; ct < 4; ++ct) {
        float bv = bias[colBase + ct * 16 + m16];
        #pragma unroll
        for (int rt = 0; rt < 2; ++rt)
            #pragma unroll
            for (int r = 0; r < 4; ++r) {
                int row = rowBase + (2 * w + rt) * 16 + quad * 4 + r;
                out[row * 128 + colBase + ct * 16 + m16] = acc[rt][ct][r] + bv;
            }
    }
}

extern "C" void kernel_launch(void* const* d_in, const int* in_sizes, int n_in,
                              void* d_out, int out_size, void* d_ws, size_t ws_size,
                              hipStream_t stream) {
    const float* pts_r1 = (const float*)d_in[0];   // (2,8192,3)
    const float* pts_r2 = (const float*)d_in[1];   // (2,4096,3)
    const float* pts_r4 = (const float*)d_in[2];   // (2,2048,3)
    const float* feat0  = (const float*)d_in[3];   // (16384,128)
    const float* feat1  = (const float*)d_in[4];   // (8192,128)
    const float* feat2  = (const float*)d_in[5];   // (4096,128)
    const float* w3a = (const float*)d_in[6];      // (128,256)
    const float* g3  = (const float*)d_in[7];
    const float* b3  = (const float*)d_in[8];
    const float* w3b = (const float*)d_in[9];      // (128,128)
    const float* bb3 = (const float*)d_in[10];
    const float* w4a = (const float*)d_in[11];     // (128,256)
    const float* g4  = (const float*)d_in[12];
    const float* b4  = (const float*)d_in[13];
    const float* w4b = (const float*)d_in[14];     // (128,128)
    const float* bb4 = (const float*)d_in[15];

    // ws layout (floats), ~17.0 MB -- under proven-safe 21.4 MB.
    float* wsf = (float*)d_ws;
    float4* sorted4 = (float4*)(wsf + 0);        // 2*2048 float4 = 16384 floats
    float4* sorted2 = (float4*)(wsf + 16384);    // 2*4096 float4 = 32768 floats
    int*   start4   = (int*)(wsf + 49152);       // 2*513 -> pad 1152
    int*   start2   = (int*)(wsf + 50304);       // 2*1001 -> pad 2048
    float* st1 = wsf + 52352;                    // 256 (sum | sumsq)
    float* ss1 = wsf + 52608;                    // 256 (scale | shift)
    float* st2 = wsf + 52864;                    // 256
    float* ss2 = wsf + 53120;                    // 256 -> 53376
    float* f2i = wsf + 53376;                    // 8192*128
    float* H1  = wsf + 1101952;                  // 8192*128
    float* n3  = wsf + 2150528;                  // 8192*128
    float* n3i = wsf + 53376;                    // 16384*128 (over f2i+H1, both dead)
    float* H2  = wsf + 2150528;                  // 16384*128 (over n3, dead by then)

    // 1. build both grids (+zero stats): 4 blocks = 2 grids x 2 batches
    build_grid_kernel<<<4, 1024, 0, stream>>>(pts_r4, pts_r2, sorted4, start4,
                                              sorted2, start2, st1, st2);
    // 2. interp #1: feat2 (pts_r4 grid, G=8) -> pts_r2 targets
    nn_query_gather_kernel<8><<<dim3(128, 2), 256, 0, stream>>>(pts_r2, 4096, sorted4,
                                                                start4, 2048, feat2, f2i);
    // 3. fnode 3
    gemm_a_kernel<<<dim3(2, 64), 256, 0, stream>>>(feat1, f2i, w3a, H1, st1);
    finalize_kernel<<<1, 128, 0, stream>>>(st1, g3, b3, 1.f / 8192.f, ss1);
    gemm_b_kernel<<<dim3(2, 64), 256, 0, stream>>>(H1, ss1, w3b, bb3, n3);
    // 4. interp #2: n3 (pts_r2 grid, G=10) -> pts_r1 targets
    nn_query_gather_kernel<10><<<dim3(256, 2), 256, 0, stream>>>(pts_r1, 8192, sorted2,
                                                                 start2, 4096, n3, n3i);
    // 5. fnode 4
    gemm_a_kernel<<<dim3(2, 128), 256, 0, stream>>>(feat0, n3i, w4a, H2, st2);
    finalize_kernel<<<1, 128, 0, stream>>>(st2, g4, b4, 1.f / 16384.f, ss2);
    gemm_b_kernel<<<dim3(2, 128), 256, 0, stream>>>(H2, ss2, w4b, bb4, (float*)d_out);
}